// Round 4
// baseline (503.969 us; speedup 1.0000x reference)
//
#include <hip/hip_runtime.h>
#include <hip/hip_bf16.h>

#define B_    32
#define DQ_   512
#define DK_   512
#define NK_   16
#define H_    8
#define TNC_  158976   // 12*207*64
#define CBLK_ 621      // TNC_/256

typedef float f32x4 __attribute__((ext_vector_type(4)));

// ---------------------------------------------------------------------------
// Kernel A: att_pre[b,k] = sum_h sum_q Q[b,q] * relu( sum_d keys[b,d,k]*W[h,q,d] + bias[h,q] )
// Grid: 512 blocks = (qhalf, b, h) with h = blockIdx.x & 7 (XCD affinity for W[h]).
// Each thread owns one q column; keys reads are wave-uniform -> scalar/broadcast
// loads (no LDS staging for keys). W rows are streamed once per thread (float4).
// ---------------------------------------------------------------------------
__global__ __launch_bounds__(256) void attA_kernel(
    const float* __restrict__ query,   // [B, DQ]
    const float* __restrict__ keys,    // [B, DK, NK]
    const float* __restrict__ W,       // [H, DQ, DK]
    const float* __restrict__ bias,    // [H, DQ]
    float* __restrict__ att_pre)       // [B, NK], pre-zeroed
{
    const int i  = blockIdx.x;
    const int h  = i & 7;
    const int b  = (i >> 3) & 31;
    const int qh = i >> 8;                    // 0 or 1
    const int q  = qh * 256 + threadIdx.x;

    const float* __restrict__ kb   = keys + (size_t)b * (DK_ * NK_);       // [512][16]
    const float* __restrict__ wrow = W + ((size_t)h * DQ_ + q) * DK_;      // 512 floats
    const float  bq = bias[h * DQ_ + q];
    const float  Qv = query[b * DQ_ + q];

    float acc[NK_];
#pragma unroll
    for (int k = 0; k < NK_; ++k) acc[k] = 0.0f;

#pragma unroll 4
    for (int d4 = 0; d4 < DK_ / 4; ++d4) {
        const float4 w = *(const float4*)(wrow + d4 * 4);
        const float wj[4] = {w.x, w.y, w.z, w.w};
#pragma unroll
        for (int j = 0; j < 4; ++j) {
            const float* __restrict__ kd = kb + (d4 * 4 + j) * NK_;  // uniform addr
#pragma unroll
            for (int k = 0; k < NK_; ++k)
                acc[k] = fmaf(wj[j], kd[k], acc[k]);
        }
    }

    // relu + dot with Q
    float c[NK_];
#pragma unroll
    for (int k = 0; k < NK_; ++k) {
        float s = acc[k] + bq;
        s = fmaxf(s, 0.0f);
        c[k] = Qv * s;
    }

    // reduce across 64 lanes (butterfly)
#pragma unroll
    for (int off = 32; off > 0; off >>= 1) {
#pragma unroll
        for (int k = 0; k < NK_; ++k)
            c[k] += __shfl_xor(c[k], off);
    }

    __shared__ float wsum[4][NK_];
    const int wid  = threadIdx.x >> 6;
    const int lane = threadIdx.x & 63;
    if (lane == 0) {
#pragma unroll
        for (int k = 0; k < NK_; ++k) wsum[wid][k] = c[k];
    }
    __syncthreads();
    if (threadIdx.x < NK_) {
        const int k = threadIdx.x;
        float s = wsum[0][k] + wsum[1][k] + wsum[2][k] + wsum[3][k];
        atomicAdd(&att_pre[b * NK_ + k], s);   // device-scope, cross-XCD safe
    }
}

// ---------------------------------------------------------------------------
// Kernel B: att[b,k] = softmax_k( att_pre[b,k] * (1/H) / sqrt(DK) )
// 1 block, 512 threads; 16-lane shuffle groups (one group per batch row).
// ---------------------------------------------------------------------------
__global__ __launch_bounds__(512) void attB_kernel(
    const float* __restrict__ att_pre,  // [B, NK]
    float* __restrict__ att)            // [B, NK]
{
    const int t = threadIdx.x;          // t = b*16 + k
    const float scale = 0.125f / 22.627416997969522f;  // (1/H)/sqrt(512)
    float x = att_pre[t] * scale;

    float m = x;
#pragma unroll
    for (int off = 8; off > 0; off >>= 1)
        m = fmaxf(m, __shfl_xor(m, off, 16));
    float e = expf(x - m);
    float s = e;
#pragma unroll
    for (int off = 8; off > 0; off >>= 1)
        s += __shfl_xor(s, off, 16);
    att[t] = e / s;
}

// ---------------------------------------------------------------------------
// Kernel C: out[b, tnc] = sum_k att[b,k] * V[b, tnc, k]   (k innermost, 16 floats)
// One output element per thread; 4x float4 non-temporal V loads (64B/lane =
// 4KB/wave, coalesced, zero-reuse stream). att[b] via wave-uniform loads.
// ---------------------------------------------------------------------------
__global__ __launch_bounds__(256) void attC_kernel(
    const float* __restrict__ att,   // [B, NK]
    const float* __restrict__ V,     // [B, TNC, NK]
    float* __restrict__ out)         // [B, TNC]
{
    const int b   = blockIdx.y;
    const int idx = blockIdx.x * 256 + threadIdx.x;   // < TNC_

    const float* __restrict__ ab = att + b * NK_;     // uniform
    const float4 a0 = *(const float4*)(ab + 0);
    const float4 a1 = *(const float4*)(ab + 4);
    const float4 a2 = *(const float4*)(ab + 8);
    const float4 a3 = *(const float4*)(ab + 12);

    const size_t row = (size_t)b * TNC_ + idx;
    const f32x4* __restrict__ vp = (const f32x4*)(V + row * NK_);
    const f32x4 v0 = __builtin_nontemporal_load(vp + 0);
    const f32x4 v1 = __builtin_nontemporal_load(vp + 1);
    const f32x4 v2 = __builtin_nontemporal_load(vp + 2);
    const f32x4 v3 = __builtin_nontemporal_load(vp + 3);

    float r = 0.0f;
    r = fmaf(a0.x, v0.x, r); r = fmaf(a0.y, v0.y, r);
    r = fmaf(a0.z, v0.z, r); r = fmaf(a0.w, v0.w, r);
    r = fmaf(a1.x, v1.x, r); r = fmaf(a1.y, v1.y, r);
    r = fmaf(a1.z, v1.z, r); r = fmaf(a1.w, v1.w, r);
    r = fmaf(a2.x, v2.x, r); r = fmaf(a2.y, v2.y, r);
    r = fmaf(a2.z, v2.z, r); r = fmaf(a2.w, v2.w, r);
    r = fmaf(a3.x, v3.x, r); r = fmaf(a3.y, v3.y, r);
    r = fmaf(a3.z, v3.z, r); r = fmaf(a3.w, v3.w, r);
    __builtin_nontemporal_store(r, out + row);
}

// ---------------------------------------------------------------------------
extern "C" void kernel_launch(void* const* d_in, const int* in_sizes, int n_in,
                              void* d_out, int out_size, void* d_ws, size_t ws_size,
                              hipStream_t stream) {
    const float* query = (const float*)d_in[0];   // [B, DQ]
    const float* keys  = (const float*)d_in[1];   // [B, DK, NK]
    const float* V     = (const float*)d_in[2];   // [B, T, N, C, NK]
    const float* W     = (const float*)d_in[3];   // [H, DQ, DK]
    const float* bias  = (const float*)d_in[4];   // [H, DQ]
    float* out = (float*)d_out;

    float* att_pre = (float*)d_ws;            // [B*NK] = 512 floats
    float* att     = att_pre + B_ * NK_;      // [B*NK]

    hipMemsetAsync(att_pre, 0, B_ * NK_ * sizeof(float), stream);
    attA_kernel<<<512, 256, 0, stream>>>(query, keys, W, bias, att_pre);
    attB_kernel<<<1, 512, 0, stream>>>(att_pre, att);
    attC_kernel<<<dim3(CBLK_, B_), 256, 0, stream>>>(att, V, out);
}

// Round 9
// 502.228 us; speedup vs baseline: 1.0035x; 1.0035x over previous
//
#include <hip/hip_runtime.h>
#include <hip/hip_bf16.h>

#define B_    32
#define DQ_   512
#define DK_   512
#define NK_   16
#define H_    8
#define TNC_  158976   // 12*207*64
#define CBLK_ 621      // TNC_/256

typedef float f32x4 __attribute__((ext_vector_type(4)));

// ---------------------------------------------------------------------------
// Kernel A: partial[b][slot][k] = sum_{q in slice} Q[b,q] * relu( sum_d keys[b,d,k]*W[h,q,d] + bias[h,q] )
// slot = qh*8 + h. Grid: 512 blocks = (qhalf, b, h), h = blockIdx.x & 7 so all
// blocks sharing W[h] land on the same XCD under round-robin dispatch (L2 reuse).
// Each thread owns one q column; keys addresses are lane-invariant -> scalar
// (broadcast) loads; W rows streamed once as float4. No atomics, no memset.
// ---------------------------------------------------------------------------
__global__ __launch_bounds__(256) void attA_kernel(
    const float* __restrict__ query,   // [B, DQ]
    const float* __restrict__ keys,    // [B, DK, NK]
    const float* __restrict__ W,       // [H, DQ, DK]
    const float* __restrict__ bias,    // [H, DQ]
    float* __restrict__ partial)       // [B, 16, NK]
{
    const int i  = blockIdx.x;
    const int h  = i & 7;
    const int b  = (i >> 3) & 31;
    const int qh = i >> 8;                    // 0 or 1
    const int q  = qh * 256 + threadIdx.x;

    const float* __restrict__ kb   = keys + (size_t)b * (DK_ * NK_);       // [512][16]
    const float* __restrict__ wrow = W + ((size_t)h * DQ_ + q) * DK_;      // 512 floats
    const float  bq = bias[h * DQ_ + q];
    const float  Qv = query[b * DQ_ + q];

    float acc[NK_];
#pragma unroll
    for (int k = 0; k < NK_; ++k) acc[k] = 0.0f;

#pragma unroll 4
    for (int d4 = 0; d4 < DK_ / 4; ++d4) {
        const float4 w = *(const float4*)(wrow + d4 * 4);
        const float wj[4] = {w.x, w.y, w.z, w.w};
#pragma unroll
        for (int j = 0; j < 4; ++j) {
            const float* __restrict__ kd = kb + (d4 * 4 + j) * NK_;  // lane-invariant addr
#pragma unroll
            for (int k = 0; k < NK_; ++k)
                acc[k] = fmaf(wj[j], kd[k], acc[k]);
        }
    }

    // relu + dot with Q
    float c[NK_];
#pragma unroll
    for (int k = 0; k < NK_; ++k) {
        float s = acc[k] + bq;
        s = fmaxf(s, 0.0f);
        c[k] = Qv * s;
    }

    // reduce across 64 lanes (butterfly)
#pragma unroll
    for (int off = 32; off > 0; off >>= 1) {
#pragma unroll
        for (int k = 0; k < NK_; ++k)
            c[k] += __shfl_xor(c[k], off);
    }

    __shared__ float wsum[4][NK_];
    const int wid  = threadIdx.x >> 6;
    const int lane = threadIdx.x & 63;
    if (lane == 0) {
#pragma unroll
        for (int k = 0; k < NK_; ++k) wsum[wid][k] = c[k];
    }
    __syncthreads();
    if (threadIdx.x < NK_) {
        const int k = threadIdx.x;
        float s = wsum[0][k] + wsum[1][k] + wsum[2][k] + wsum[3][k];
        partial[((b * 16) + (qh * 8 + h)) * NK_ + k] = s;   // private slot, no atomic
    }
}

// ---------------------------------------------------------------------------
// Kernel B: att[b,k] = softmax_k( (1/H)/sqrt(DK) * sum_slot partial[b,slot,k] )
// 1 block, 512 threads = (b,k); 16-lane shuffle groups (one group per batch row).
// ---------------------------------------------------------------------------
__global__ __launch_bounds__(512) void attB_kernel(
    const float* __restrict__ partial,  // [B, 16, NK]
    float* __restrict__ att)            // [B, NK]
{
    const int t = threadIdx.x;          // t = b*16 + k
    const int b = t >> 4;
    const int k = t & 15;

    float x = 0.0f;
#pragma unroll
    for (int s = 0; s < 16; ++s)
        x += partial[((b * 16) + s) * NK_ + k];

    const float scale = 0.125f / 22.627416997969522f;  // (1/H)/sqrt(512)
    x *= scale;

    float m = x;
#pragma unroll
    for (int off = 8; off > 0; off >>= 1)
        m = fmaxf(m, __shfl_xor(m, off, 16));
    float e = expf(x - m);
    float s = e;
#pragma unroll
    for (int off = 8; off > 0; off >>= 1)
        s += __shfl_xor(s, off, 16);
    att[t] = e / s;
}

// ---------------------------------------------------------------------------
// Kernel C: out[b, tnc] = sum_k att[b,k] * V[b, tnc, k]   (k innermost, 16 floats)
// One output element per thread; 4x float4 non-temporal V loads (64B/lane =
// 4KB/wave, coalesced, zero-reuse stream). att[b] via lane-invariant loads.
// ---------------------------------------------------------------------------
__global__ __launch_bounds__(256) void attC_kernel(
    const float* __restrict__ att,   // [B, NK]
    const float* __restrict__ V,     // [B, TNC, NK]
    float* __restrict__ out)         // [B, TNC]
{
    const int b   = blockIdx.y;
    const int idx = blockIdx.x * 256 + threadIdx.x;   // < TNC_

    const float* __restrict__ ab = att + b * NK_;     // lane-invariant
    const float4 a0 = *(const float4*)(ab + 0);
    const float4 a1 = *(const float4*)(ab + 4);
    const float4 a2 = *(const float4*)(ab + 8);
    const float4 a3 = *(const float4*)(ab + 12);

    const size_t row = (size_t)b * TNC_ + idx;
    const f32x4* __restrict__ vp = (const f32x4*)(V + row * NK_);
    const f32x4 v0 = __builtin_nontemporal_load(vp + 0);
    const f32x4 v1 = __builtin_nontemporal_load(vp + 1);
    const f32x4 v2 = __builtin_nontemporal_load(vp + 2);
    const f32x4 v3 = __builtin_nontemporal_load(vp + 3);

    float r = 0.0f;
    r = fmaf(a0.x, v0.x, r); r = fmaf(a0.y, v0.y, r);
    r = fmaf(a0.z, v0.z, r); r = fmaf(a0.w, v0.w, r);
    r = fmaf(a1.x, v1.x, r); r = fmaf(a1.y, v1.y, r);
    r = fmaf(a1.z, v1.z, r); r = fmaf(a1.w, v1.w, r);
    r = fmaf(a2.x, v2.x, r); r = fmaf(a2.y, v2.y, r);
    r = fmaf(a2.z, v2.z, r); r = fmaf(a2.w, v2.w, r);
    r = fmaf(a3.x, v3.x, r); r = fmaf(a3.y, v3.y, r);
    r = fmaf(a3.z, v3.z, r); r = fmaf(a3.w, v3.w, r);
    __builtin_nontemporal_store(r, out + row);
}

// ---------------------------------------------------------------------------
extern "C" void kernel_launch(void* const* d_in, const int* in_sizes, int n_in,
                              void* d_out, int out_size, void* d_ws, size_t ws_size,
                              hipStream_t stream) {
    const float* query = (const float*)d_in[0];   // [B, DQ]
    const float* keys  = (const float*)d_in[1];   // [B, DK, NK]
    const float* V     = (const float*)d_in[2];   // [B, T, N, C, NK]
    const float* W     = (const float*)d_in[3];   // [H, DQ, DK]
    const float* bias  = (const float*)d_in[4];   // [H, DQ]
    float* out = (float*)d_out;

    float* partial = (float*)d_ws;                 // [B*16*NK] = 8192 floats
    float* att     = partial + B_ * 16 * NK_;      // [B*NK]

    attA_kernel<<<512, 256, 0, stream>>>(query, keys, W, bias, partial);
    attB_kernel<<<1, 512, 0, stream>>>(partial, att);
    attC_kernel<<<dim3(CBLK_, B_), 256, 0, stream>>>(att, V, out);
}